// Round 3
// baseline (202.531 us; speedup 1.0000x reference)
//
#include <hip/hip_runtime.h>
#include <hip/hip_bf16.h>
#include <float.h>

// Problem constants
#define N_ROWS 32768          // 32 * 1024 query vectors
#define DIMS   64
#define K_EMB  8192
#define NT     (K_EMB / 16)   // 512 column tiles of 16
#define NQ     16             // K split into 16 slices (grid parallelism + load balance)
#define NTQ    (NT / NQ)      // 32 tiles per slice
#define TSTAGE 4              // tiles staged per barrier round (16 KB)
#define NSTAGE (NTQ / TSTAGE) // 8
#define RG     4              // row-groups (16 rows each) per wave -> 64 rows/wave
// 3-term split-bf16 worst-case f-error ~6.5e-4; 1.5e-3 gives >2x margin.
#define GAP_THR 1.5e-3f

typedef __attribute__((ext_vector_type(8))) short s8v;   // 8 bf16 (A/B frag)
typedef __attribute__((ext_vector_type(4))) float f4v;   // C/D frag
typedef __attribute__((ext_vector_type(4))) int   i4v;   // 16B load unit

// Workspace layout (bytes) — total ~8.9 MB
#define WS_EFRAG 0                              // 2 MiB
#define WS_EN2   (2 * 1024 * 1024)              // 8192 f32: -0.5*||e||^2
#define WS_IDX   (WS_EN2 + K_EMB * 4)           // 32768 i32 (merged idx)
#define WS_KEY   (WS_IDX + N_ROWS * 4)          // 32768 u64 fixup keys
#define WS_BH    (WS_KEY + N_ROWS * 8)          // [NQ][N] best per slice (then nb)
#define WS_SH    (WS_BH + NQ * N_ROWS * 4)      // [NQ][N] second
#define WS_CH    (WS_SH + NQ * N_ROWS * 4)      // [NQ][N] idx
#define WS_CTL   (WS_CH + NQ * N_ROWS * 4)      // {double loss; int wl_count; pad}
#define WS_WL    (WS_CTL + 16)                  // worklist

// Output layout (float32 elements): [quantized | loss | indices]
#define OUT_LOSS (N_ROWS * DIMS)
#define OUT_IDX  (N_ROWS * DIMS + 1)

__device__ inline short bfh(float v) {
    __hip_bfloat16 h = __float2bfloat16(v);
    return __builtin_bit_cast(short, h);
}
__device__ inline float bff(short s) {
    __hip_bfloat16 h = __builtin_bit_cast(__hip_bfloat16, s);
    return __bfloat162float(h);
}

// ---------------------------------------------------------------------------
// Prep: embeddings -> MFMA B-frag layout (hi/lo bf16 split) + fused -||e||^2/2.
// B-frag: lane holds B[k=(lane>>4)*8+j][n=lane&15]. Frags: 0=hi k[0,32),
// 1=hi k[32,64), 2=lo k[0,32), 3=lo k[32,64). [tile][frag][lane][16B].
// Also zeroes the CTL block (loss acc + wl_count) — replaces a memset dispatch
// (stream order guarantees visibility to merge/gather).
// ---------------------------------------------------------------------------
__global__ void vq_prep(const float* __restrict__ emb, short* __restrict__ efrag,
                        float* __restrict__ en2, int4* __restrict__ ctl) {
    if (blockIdx.x == 0 && threadIdx.x == 0) *ctl = make_int4(0, 0, 0, 0);
    int gid = blockIdx.x * 256 + threadIdx.x;   // NT*64 = 32768 threads
    int t = gid >> 6, lane = gid & 63;
    int m = lane & 15, q = lane >> 4;
    const float* er = emb + (size_t)(t * 16 + m) * DIMS;
    s8v hi0, lo0, hi1, lo1;
    float ss = 0.f;
#pragma unroll
    for (int j = 0; j < 8; ++j) {
        float v0 = er[q * 8 + j];
        float v1 = er[32 + q * 8 + j];
        ss += v0 * v0 + v1 * v1;
        short h0 = bfh(v0); lo0[j] = bfh(v0 - bff(h0)); hi0[j] = h0;
        short h1 = bfh(v1); lo1[j] = bfh(v1 - bff(h1)); hi1[j] = h1;
    }
    s8v* base = (s8v*)efrag + (size_t)t * 4 * 64;
    base[0 * 64 + lane] = hi0;
    base[1 * 64 + lane] = hi1;
    base[2 * 64 + lane] = lo0;
    base[3 * 64 + lane] = lo1;
    // reduce sum of squares across the 4 q-lanes sharing m
    ss += __shfl_xor(ss, 16, 64);
    ss += __shfl_xor(ss, 32, 64);
    if (q == 0) en2[t * 16 + m] = -0.5f * ss;
}

// ---------------------------------------------------------------------------
// Phase 1: LDS-staged split-bf16 MFMA distance + per-K-slice argmax/second.
// Grid (128, 16): blockIdx.x = row-block (256 rows), blockIdx.y = K-slice.
// 4 waves x 64 rows (RG=4 groups of 16): each staged B tile read ONCE per wave
// feeds 24 MFMAs (vs 12 before) -> LDS pipe time halved (the pipes were
// additive: MFMA 50us + LDS 41us + VALU 20us ~= measured 113us).
// VGPR ~150 natural -> (256,3): cap 170, never cap below need (round-1 lesson).
// ---------------------------------------------------------------------------
__global__ __launch_bounds__(256, 3) void vq_phase1(
    const float* __restrict__ x, const short* __restrict__ efrag,
    const float* __restrict__ en2,
    float* __restrict__ bh, float* __restrict__ sh, int* __restrict__ ch) {
    __shared__ __align__(16) char lds[2][TSTAGE * 4096];   // 32 KB
    int tid = threadIdx.x, wid = tid >> 6, lane = tid & 63;
    int m = lane & 15, q = lane >> 4;
    int kh = blockIdx.y;
    int row0 = blockIdx.x * 256 + wid * 64;

    // A-frags for RG row-groups: A[m][k=quad*8+j], hi/lo, two K-halves of dims.
    s8v ahi[RG][2], alo[RG][2];
#pragma unroll
    for (int g = 0; g < RG; ++g) {
        const float* xr = x + (size_t)(row0 + g * 16 + m) * DIMS + q * 8;
#pragma unroll
        for (int j = 0; j < 8; ++j) {
            float v0 = xr[j], v1 = xr[32 + j];
            short h0 = bfh(v0); alo[g][0][j] = bfh(v0 - bff(h0)); ahi[g][0][j] = h0;
            short h1 = bfh(v1); alo[g][1][j] = bfh(v1 - bff(h1)); ahi[g][1][j] = h1;
        }
    }

    float best[RG][4], sec[RG][4];
    int bc[RG][4];
#pragma unroll
    for (int g = 0; g < RG; ++g)
#pragma unroll
        for (int r = 0; r < 4; ++r) { best[g][r] = -FLT_MAX; sec[g][r] = -FLT_MAX; bc[g][r] = 0; }

    const char* gsrc = (const char*)efrag + (size_t)kh * NTQ * 4096;

    // preload stage 0
#pragma unroll
    for (int i = 0; i < TSTAGE; ++i)
        __builtin_amdgcn_global_load_lds(
            (const __attribute__((address_space(1))) void*)(gsrc + i * 4096 + tid * 16),
            (__attribute__((address_space(3))) void*)(&lds[0][i * 4096 + tid * 16]),
            16, 0, 0);
    __syncthreads();

    for (int s = 0; s < NSTAGE; ++s) {
        int pb = s & 1;
        if (s + 1 < NSTAGE) {
            const char* gn = gsrc + (size_t)(s + 1) * TSTAGE * 4096;
#pragma unroll
            for (int i = 0; i < TSTAGE; ++i)
                __builtin_amdgcn_global_load_lds(
                    (const __attribute__((address_space(1))) void*)(gn + i * 4096 + tid * 16),
                    (__attribute__((address_space(3))) void*)(&lds[pb ^ 1][i * 4096 + tid * 16]),
                    16, 0, 0);
        }
        const i4v* B = (const i4v*)(lds[pb]);
        int tg0 = kh * NTQ + s * TSTAGE;
        const float* ep = en2 + (size_t)tg0 * 16 + m;
#pragma unroll
        for (int tt = 0; tt < TSTAGE; ++tt) {
            i4v b0 = B[tt * 256 + 0 * 64 + lane];
            i4v b1 = B[tt * 256 + 1 * 64 + lane];
            i4v b2 = B[tt * 256 + 2 * 64 + lane];
            i4v b3 = B[tt * 256 + 3 * 64 + lane];
            float c0 = ep[tt * 16];
            int cidx = (tg0 + tt) * 16 + m;
            f4v cinit = {c0, c0, c0, c0};   // C init = -||e_col||^2 / 2 (D!=C: no copy)
#pragma unroll
            for (int g = 0; g < RG; ++g) {
                f4v acc;
                acc = __builtin_amdgcn_mfma_f32_16x16x32_bf16(ahi[g][0], __builtin_bit_cast(s8v, b0), cinit, 0, 0, 0);
                acc = __builtin_amdgcn_mfma_f32_16x16x32_bf16(ahi[g][1], __builtin_bit_cast(s8v, b1), acc, 0, 0, 0);
                acc = __builtin_amdgcn_mfma_f32_16x16x32_bf16(ahi[g][0], __builtin_bit_cast(s8v, b2), acc, 0, 0, 0);
                acc = __builtin_amdgcn_mfma_f32_16x16x32_bf16(ahi[g][1], __builtin_bit_cast(s8v, b3), acc, 0, 0, 0);
                acc = __builtin_amdgcn_mfma_f32_16x16x32_bf16(alo[g][0], __builtin_bit_cast(s8v, b0), acc, 0, 0, 0);
                acc = __builtin_amdgcn_mfma_f32_16x16x32_bf16(alo[g][1], __builtin_bit_cast(s8v, b1), acc, 0, 0, 0);
#pragma unroll
                for (int r = 0; r < 4; ++r) {   // C/D: col=lane&15, row=quad*4+r
                    float v = acc[r];
                    bool gt = v > best[g][r];
                    // exact: new second-best = median(v, sec, best)  (sec <= best)
                    sec[g][r]  = __builtin_amdgcn_fmed3f(v, sec[g][r], best[g][r]);
                    best[g][r] = fmaxf(best[g][r], v);
                    bc[g][r]   = gt ? cidx : bc[g][r];
                }
            }
        }
        __syncthreads();
    }

    // Reduce (best, idx, second) across the 16 col-lanes of each quad.
#pragma unroll
    for (int g = 0; g < RG; ++g)
#pragma unroll
    for (int r = 0; r < 4; ++r) {
        float b = best[g][r], s = sec[g][r];
        int c = bc[g][r];
#pragma unroll
        for (int off = 1; off < 16; off <<= 1) {
            float ob = __shfl_xor(b, off, 64);
            float os = __shfl_xor(s, off, 64);
            int   oc = __shfl_xor(c, off, 64);
            float nb = fmaxf(b, ob);
            float ns = fmaxf(fminf(b, ob), fmaxf(s, os));
            bool take = (ob > b) || (ob == b && oc < c);  // tie -> lowest index
            c = take ? oc : c;
            b = nb; s = ns;
        }
        if (m == 0) {
            int o = kh * N_ROWS + row0 + g * 16 + q * 4 + r;
            bh[o] = b; sh[o] = s; ch[o] = c;
        }
    }
}

// ---------------------------------------------------------------------------
// Merge the NQ K-slices per row; store merged best value (for fixup
// prefilter); zero fixup keys; build worklist.
// ---------------------------------------------------------------------------
__global__ void vq_merge(const float* __restrict__ bh, const float* __restrict__ sh,
                         const int* __restrict__ ch, int* __restrict__ idx_buf,
                         unsigned long long* __restrict__ key8,
                         float* __restrict__ nbv,
                         int* __restrict__ wl, int* __restrict__ wl_count) {
    int row = blockIdx.x * 256 + threadIdx.x;
    float nb = bh[row];
    int   c  = ch[row];
    float ns = -FLT_MAX;
#pragma unroll
    for (int h = 1; h < NQ; ++h) {
        float b = bh[h * N_ROWS + row];
        int   cc = ch[h * N_ROWS + row];
        if (b > nb) { ns = nb; nb = b; c = cc; }   // tie -> lowest slice (lower cols)
        else        { ns = fmaxf(ns, b); }
    }
#pragma unroll
    for (int h = 0; h < NQ; ++h) ns = fmaxf(ns, sh[h * N_ROWS + row]);
    idx_buf[row] = c;
    key8[row] = 0ULL;
    nbv[row] = nb;
    if (nb - ns < GAP_THR) {
        int pos = atomicAdd(wl_count, 1);
        wl[pos] = row;
    }
}

// ---------------------------------------------------------------------------
// Fixup: exact fp32 rescan. One wave per 64-column chunk; each lane owns one
// embedding column kept entirely in registers (16 float4), looping over the
// worklist rows (x row loads are wave-uniform -> scalar loads). Candidates
// merged via atomicMax on packed (sortable(f) << 32 | ~idx) — exact argmax,
// ties->low idx. Prefilter: local max must be within GAP_THR of the merged
// approx best (exact winner always passes since |approx-exact| <= 6.5e-4).
// ---------------------------------------------------------------------------
__global__ __launch_bounds__(64) void vq_fixup(
    const float* __restrict__ x, const float* __restrict__ emb,
    const float* __restrict__ en2, const float* __restrict__ nbv,
    unsigned long long* __restrict__ key8,
    const int* __restrict__ wl, const int* __restrict__ wl_count) {
    int lane = threadIdx.x;                 // 64 threads = 1 wave
    int cchunk = blockIdx.x & 127;          // 128 col-chunks of 64
    int rslice = blockIdx.x >> 7;           // 16 row slices
    int c = cchunk * 64 + lane;
    const float4* er = (const float4*)(emb + (size_t)c * DIMS);
    float4 e[16];
#pragma unroll
    for (int qq = 0; qq < 16; ++qq) e[qq] = er[qq];
    float c0 = en2[c];
    int cnt = *wl_count;
    for (int wi = rslice; wi < cnt; wi += 16) {
        int row = wl[wi];
        const float4* xr = (const float4*)(x + (size_t)row * DIMS);
        float d = 0.f;
#pragma unroll
        for (int qq = 0; qq < 16; ++qq) {
            float4 ee = e[qq];
            float4 xx = xr[qq];
            d += ee.x * xx.x + ee.y * xx.y + ee.z * xx.z + ee.w * xx.w;
        }
        float bf_ = d + c0;
        int bc_ = c;
#pragma unroll
        for (int off = 1; off < 64; off <<= 1) {
            float of = __shfl_xor(bf_, off, 64);
            int   oc = __shfl_xor(bc_, off, 64);
            if (of > bf_ || (of == bf_ && oc < bc_)) { bf_ = of; bc_ = oc; }
        }
        if (lane == 0 && bf_ >= nbv[row] - GAP_THR) {
            unsigned int u = __float_as_uint(bf_);
            unsigned int sb = ((int)u < 0) ? ~u : (u | 0x80000000u);
            unsigned long long key = ((unsigned long long)sb << 32) | (unsigned int)(~bc_);
            atomicMax(&key8[row], key);
        }
    }
}

// ---------------------------------------------------------------------------
// Gather quantized rows, accumulate squared error, emit indices as floats.
// ---------------------------------------------------------------------------
__global__ void vq_gather(const float* __restrict__ x, const float* __restrict__ emb,
                          const int* __restrict__ idx_buf,
                          const unsigned long long* __restrict__ key8,
                          float* __restrict__ out, double* __restrict__ loss_acc) {
    int row = blockIdx.x * blockDim.x + threadIdx.x;
    unsigned long long k = key8[row];
    int idx = k ? (int)(~(unsigned int)k) : idx_buf[row];
    const float4* ev = (const float4*)(emb + (size_t)idx * DIMS);
    const float4* xv = (const float4*)(x + (size_t)row * DIMS);
    float4* ov = (float4*)(out + (size_t)row * DIMS);
    float s = 0.f;
#pragma unroll
    for (int qq = 0; qq < 16; ++qq) {
        float4 ee = ev[qq];
        float4 xx = xv[qq];
        float dx = ee.x - xx.x, dy = ee.y - xx.y, dz = ee.z - xx.z, dw = ee.w - xx.w;
        s += dx * dx + dy * dy + dz * dz + dw * dw;
        ov[qq] = ee;
    }
#pragma unroll
    for (int off = 32; off > 0; off >>= 1) s += __shfl_down(s, off, 64);
    if ((threadIdx.x & 63) == 0) atomicAdd(loss_acc, (double)s);
    out[OUT_IDX + row] = (float)idx;
}

__global__ void vq_loss(const double* __restrict__ acc, float* __restrict__ out) {
    out[OUT_LOSS] = (float)(1.25 * (*acc) / (double)(N_ROWS * DIMS));
}

// ---------------------------------------------------------------------------
extern "C" void kernel_launch(void* const* d_in, const int* in_sizes, int n_in,
                              void* d_out, int out_size, void* d_ws, size_t ws_size,
                              hipStream_t stream) {
    const float* x   = (const float*)d_in[0];
    const float* emb = (const float*)d_in[1];
    float* out = (float*)d_out;
    char*  ws  = (char*)d_ws;

    short* efrag   = (short*)(ws + WS_EFRAG);
    float* en2     = (float*)(ws + WS_EN2);
    int*   idx_buf = (int*)(ws + WS_IDX);
    unsigned long long* key8 = (unsigned long long*)(ws + WS_KEY);
    float* bhb     = (float*)(ws + WS_BH);
    float* shb     = (float*)(ws + WS_SH);
    int*   chb     = (int*)(ws + WS_CH);
    double* loss_acc = (double*)(ws + WS_CTL);
    int*   wl_count  = (int*)(ws + WS_CTL + 8);
    int*   wl        = (int*)(ws + WS_WL);

    vq_prep<<<(NT * 64) / 256, 256, 0, stream>>>(emb, efrag, en2, (int4*)(ws + WS_CTL));  // 128 blocks
    vq_phase1<<<dim3(N_ROWS / 256, NQ), 256, 0, stream>>>(x, efrag, en2, bhb, shb, chb);  // 2048 blocks
    vq_merge<<<N_ROWS / 256, 256, 0, stream>>>(bhb, shb, chb, idx_buf, key8, bhb, wl, wl_count);
    vq_fixup<<<2048, 64, 0, stream>>>(x, emb, en2, bhb, key8, wl, wl_count);
    vq_gather<<<N_ROWS / 256, 256, 0, stream>>>(x, emb, idx_buf, key8, out, loss_acc);
    vq_loss<<<1, 1, 0, stream>>>(loss_acc, out);
}

// Round 4
// 198.077 us; speedup vs baseline: 1.0225x; 1.0225x over previous
//
#include <hip/hip_runtime.h>
#include <hip/hip_bf16.h>
#include <float.h>

// Problem constants
#define N_ROWS 32768          // 32 * 1024 query vectors
#define DIMS   64
#define K_EMB  8192
#define NT     (K_EMB / 16)   // 512 column tiles of 16
#define NQ     16             // K split into 16 slices (grid parallelism + load balance)
#define NTQ    (NT / NQ)      // 32 tiles per slice
#define TSTAGE 4              // tiles staged per barrier round (16 KB)
#define NSTAGE (NTQ / TSTAGE) // 8
#define RG     4              // row-groups (16 rows each) per wave -> 64 rows/wave
// 3-term split-bf16 worst-case f-error ~6.5e-4; 1.5e-3 gives >2x margin.
#define GAP_THR 1.5e-3f

typedef __attribute__((ext_vector_type(8))) short s8v;   // 8 bf16 (A/B frag)
typedef __attribute__((ext_vector_type(4))) float f4v;   // C/D frag
typedef __attribute__((ext_vector_type(4))) int   i4v;   // 16B load unit

// Workspace layout (bytes) — total ~8.9 MB
#define WS_EFRAG 0                              // 2 MiB
#define WS_EN2   (2 * 1024 * 1024)              // 8192 f32: -0.5*||e||^2
#define WS_IDX   (WS_EN2 + K_EMB * 4)           // 32768 i32 (merged idx)
#define WS_KEY   (WS_IDX + N_ROWS * 4)          // 32768 u64 fixup keys
#define WS_BH    (WS_KEY + N_ROWS * 8)          // [NQ][N] best per slice (then nb)
#define WS_SH    (WS_BH + NQ * N_ROWS * 4)      // [NQ][N] second
#define WS_CH    (WS_SH + NQ * N_ROWS * 4)      // [NQ][N] idx
#define WS_CTL   (WS_CH + NQ * N_ROWS * 4)      // {double loss; int wl_count; int done}
#define WS_WL    (WS_CTL + 16)                  // worklist

// Output layout (float32 elements): [quantized | loss | indices]
#define OUT_LOSS (N_ROWS * DIMS)
#define OUT_IDX  (N_ROWS * DIMS + 1)

__device__ inline short bfh(float v) {
    __hip_bfloat16 h = __float2bfloat16(v);
    return __builtin_bit_cast(short, h);
}
__device__ inline float bff(short s) {
    __hip_bfloat16 h = __builtin_bit_cast(__hip_bfloat16, s);
    return __bfloat162float(h);
}

// ---------------------------------------------------------------------------
// Prep: embeddings -> MFMA B-frag layout (hi/lo bf16 split) + fused -||e||^2/2.
// B-frag: lane holds B[k=(lane>>4)*8+j][n=lane&15]. Frags: 0=hi k[0,32),
// 1=hi k[32,64), 2=lo k[0,32), 3=lo k[32,64). [tile][frag][lane][16B].
// Also zeroes the CTL block (loss acc + wl_count + done) — replaces a memset.
// ---------------------------------------------------------------------------
__global__ void vq_prep(const float* __restrict__ emb, short* __restrict__ efrag,
                        float* __restrict__ en2, int4* __restrict__ ctl) {
    if (blockIdx.x == 0 && threadIdx.x == 0) *ctl = make_int4(0, 0, 0, 0);
    int gid = blockIdx.x * 256 + threadIdx.x;   // NT*64 = 32768 threads
    int t = gid >> 6, lane = gid & 63;
    int m = lane & 15, q = lane >> 4;
    const float* er = emb + (size_t)(t * 16 + m) * DIMS;
    s8v hi0, lo0, hi1, lo1;
    float ss = 0.f;
#pragma unroll
    for (int j = 0; j < 8; ++j) {
        float v0 = er[q * 8 + j];
        float v1 = er[32 + q * 8 + j];
        ss += v0 * v0 + v1 * v1;
        short h0 = bfh(v0); lo0[j] = bfh(v0 - bff(h0)); hi0[j] = h0;
        short h1 = bfh(v1); lo1[j] = bfh(v1 - bff(h1)); hi1[j] = h1;
    }
    s8v* base = (s8v*)efrag + (size_t)t * 4 * 64;
    base[0 * 64 + lane] = hi0;
    base[1 * 64 + lane] = hi1;
    base[2 * 64 + lane] = lo0;
    base[3 * 64 + lane] = lo1;
    // reduce sum of squares across the 4 q-lanes sharing m
    ss += __shfl_xor(ss, 16, 64);
    ss += __shfl_xor(ss, 32, 64);
    if (q == 0) en2[t * 16 + m] = -0.5f * ss;
}

// ---------------------------------------------------------------------------
// Phase 1: LDS-staged split-bf16 MFMA distance + per-K-slice argmax/second.
// Grid (128, 16): blockIdx.x = row-block (256 rows), blockIdx.y = K-slice.
// 4 waves x 64 rows (RG=4 groups of 16): each staged B tile read ONCE per wave
// feeds 24 MFMAs -> per-CU LDS pipe ~41us -> ~20us (pipes are ~additive:
// MFMA 50 + LDS 41 + VALU ~20 ~= R2's measured 113us).
// Register economics: RG=4 needs ~150-160 live VGPRs. Round-3 lesson: the
// backend's occupancy heuristic ignored __launch_bounds__(256,3) and clamped
// to ~84 VGPR (-> 52MB scratch). amdgpu_waves_per_eu(2,3) pins the target:
// cap 168 at 3 waves/EU, graceful fallback to 2 (cap 256) — never spill.
// ---------------------------------------------------------------------------
__global__ __launch_bounds__(256)
__attribute__((amdgpu_waves_per_eu(2, 3))) void vq_phase1(
    const float* __restrict__ x, const short* __restrict__ efrag,
    const float* __restrict__ en2,
    float* __restrict__ bh, float* __restrict__ sh, int* __restrict__ ch) {
    __shared__ __align__(16) char lds[2][TSTAGE * 4096];   // 32 KB
    int tid = threadIdx.x, wid = tid >> 6, lane = tid & 63;
    int m = lane & 15, q = lane >> 4;
    int kh = blockIdx.y;
    int row0 = blockIdx.x * 256 + wid * 64;

    // A-frags for RG row-groups: A[m][k=quad*8+j], hi/lo, two K-halves of dims.
    s8v ahi[RG][2], alo[RG][2];
#pragma unroll
    for (int g = 0; g < RG; ++g) {
        const float* xr = x + (size_t)(row0 + g * 16 + m) * DIMS + q * 8;
#pragma unroll
        for (int j = 0; j < 8; ++j) {
            float v0 = xr[j], v1 = xr[32 + j];
            short h0 = bfh(v0); alo[g][0][j] = bfh(v0 - bff(h0)); ahi[g][0][j] = h0;
            short h1 = bfh(v1); alo[g][1][j] = bfh(v1 - bff(h1)); ahi[g][1][j] = h1;
        }
    }

    float best[RG][4], sec[RG][4];
    int bc[RG][4];
#pragma unroll
    for (int g = 0; g < RG; ++g)
#pragma unroll
        for (int r = 0; r < 4; ++r) { best[g][r] = -FLT_MAX; sec[g][r] = -FLT_MAX; bc[g][r] = 0; }

    const char* gsrc = (const char*)efrag + (size_t)kh * NTQ * 4096;

    // preload stage 0
#pragma unroll
    for (int i = 0; i < TSTAGE; ++i)
        __builtin_amdgcn_global_load_lds(
            (const __attribute__((address_space(1))) void*)(gsrc + i * 4096 + tid * 16),
            (__attribute__((address_space(3))) void*)(&lds[0][i * 4096 + tid * 16]),
            16, 0, 0);
    __syncthreads();

    for (int s = 0; s < NSTAGE; ++s) {
        int pb = s & 1;
        if (s + 1 < NSTAGE) {
            const char* gn = gsrc + (size_t)(s + 1) * TSTAGE * 4096;
#pragma unroll
            for (int i = 0; i < TSTAGE; ++i)
                __builtin_amdgcn_global_load_lds(
                    (const __attribute__((address_space(1))) void*)(gn + i * 4096 + tid * 16),
                    (__attribute__((address_space(3))) void*)(&lds[pb ^ 1][i * 4096 + tid * 16]),
                    16, 0, 0);
        }
        const i4v* B = (const i4v*)(lds[pb]);
        int tg0 = kh * NTQ + s * TSTAGE;
        const float* ep = en2 + (size_t)tg0 * 16 + m;
#pragma unroll
        for (int tt = 0; tt < TSTAGE; ++tt) {
            i4v b0 = B[tt * 256 + 0 * 64 + lane];
            i4v b1 = B[tt * 256 + 1 * 64 + lane];
            i4v b2 = B[tt * 256 + 2 * 64 + lane];
            i4v b3 = B[tt * 256 + 3 * 64 + lane];
            float c0 = ep[tt * 16];
            int cidx = (tg0 + tt) * 16 + m;
            f4v cinit = {c0, c0, c0, c0};   // C init = -||e_col||^2 / 2
#pragma unroll
            for (int g = 0; g < RG; ++g) {
                f4v acc;
                acc = __builtin_amdgcn_mfma_f32_16x16x32_bf16(ahi[g][0], __builtin_bit_cast(s8v, b0), cinit, 0, 0, 0);
                acc = __builtin_amdgcn_mfma_f32_16x16x32_bf16(ahi[g][1], __builtin_bit_cast(s8v, b1), acc, 0, 0, 0);
                acc = __builtin_amdgcn_mfma_f32_16x16x32_bf16(ahi[g][0], __builtin_bit_cast(s8v, b2), acc, 0, 0, 0);
                acc = __builtin_amdgcn_mfma_f32_16x16x32_bf16(ahi[g][1], __builtin_bit_cast(s8v, b3), acc, 0, 0, 0);
                acc = __builtin_amdgcn_mfma_f32_16x16x32_bf16(alo[g][0], __builtin_bit_cast(s8v, b0), acc, 0, 0, 0);
                acc = __builtin_amdgcn_mfma_f32_16x16x32_bf16(alo[g][1], __builtin_bit_cast(s8v, b1), acc, 0, 0, 0);
#pragma unroll
                for (int r = 0; r < 4; ++r) {   // C/D: col=lane&15, row=quad*4+r
                    float v = acc[r];
                    bool gt = v > best[g][r];
                    // exact: new second-best = median(v, sec, best)  (sec <= best)
                    sec[g][r]  = __builtin_amdgcn_fmed3f(v, sec[g][r], best[g][r]);
                    best[g][r] = fmaxf(best[g][r], v);
                    bc[g][r]   = gt ? cidx : bc[g][r];
                }
            }
        }
        __syncthreads();
    }

    // Reduce (best, idx, second) across the 16 col-lanes of each quad.
#pragma unroll
    for (int g = 0; g < RG; ++g)
#pragma unroll
    for (int r = 0; r < 4; ++r) {
        float b = best[g][r], s = sec[g][r];
        int c = bc[g][r];
#pragma unroll
        for (int off = 1; off < 16; off <<= 1) {
            float ob = __shfl_xor(b, off, 64);
            float os = __shfl_xor(s, off, 64);
            int   oc = __shfl_xor(c, off, 64);
            float nb = fmaxf(b, ob);
            float ns = fmaxf(fminf(b, ob), fmaxf(s, os));
            bool take = (ob > b) || (ob == b && oc < c);  // tie -> lowest index
            c = take ? oc : c;
            b = nb; s = ns;
        }
        if (m == 0) {
            int o = kh * N_ROWS + row0 + g * 16 + q * 4 + r;
            bh[o] = b; sh[o] = s; ch[o] = c;
        }
    }
}

// ---------------------------------------------------------------------------
// Merge the NQ K-slices per row; store merged best value (for fixup
// prefilter); zero fixup keys; build worklist.
// ---------------------------------------------------------------------------
__global__ void vq_merge(const float* __restrict__ bh, const float* __restrict__ sh,
                         const int* __restrict__ ch, int* __restrict__ idx_buf,
                         unsigned long long* __restrict__ key8,
                         float* __restrict__ nbv,
                         int* __restrict__ wl, int* __restrict__ wl_count) {
    int row = blockIdx.x * 256 + threadIdx.x;
    float nb = bh[row];
    int   c  = ch[row];
    float ns = -FLT_MAX;
#pragma unroll
    for (int h = 1; h < NQ; ++h) {
        float b = bh[h * N_ROWS + row];
        int   cc = ch[h * N_ROWS + row];
        if (b > nb) { ns = nb; nb = b; c = cc; }   // tie -> lowest slice (lower cols)
        else        { ns = fmaxf(ns, b); }
    }
#pragma unroll
    for (int h = 0; h < NQ; ++h) ns = fmaxf(ns, sh[h * N_ROWS + row]);
    idx_buf[row] = c;
    key8[row] = 0ULL;
    nbv[row] = nb;
    if (nb - ns < GAP_THR) {
        int pos = atomicAdd(wl_count, 1);
        wl[pos] = row;
    }
}

// ---------------------------------------------------------------------------
// Fixup: exact fp32 rescan. One wave per 64-column chunk; each lane owns one
// embedding column kept entirely in registers (16 float4), looping over the
// worklist rows (x row loads are wave-uniform). Candidates merged via
// atomicMax on packed (sortable(f) << 32 | ~idx) — exact argmax, ties->low
// idx. Prefilter: local max must be within GAP_THR of the merged approx best
// (exact winner always passes since |approx-exact| <= 6.5e-4).
// Early-exit BEFORE the 16KB e-preload when this block's row-slice is empty.
// ---------------------------------------------------------------------------
__global__ __launch_bounds__(64) void vq_fixup(
    const float* __restrict__ x, const float* __restrict__ emb,
    const float* __restrict__ en2, const float* __restrict__ nbv,
    unsigned long long* __restrict__ key8,
    const int* __restrict__ wl, const int* __restrict__ wl_count) {
    int lane = threadIdx.x;                 // 64 threads = 1 wave
    int cchunk = blockIdx.x & 127;          // 128 col-chunks of 64
    int rslice = blockIdx.x >> 7;           // 16 row slices
    int cnt = *wl_count;
    if (rslice >= cnt) return;              // empty slice: skip e-preload
    int c = cchunk * 64 + lane;
    const float4* er = (const float4*)(emb + (size_t)c * DIMS);
    float4 e[16];
#pragma unroll
    for (int qq = 0; qq < 16; ++qq) e[qq] = er[qq];
    float c0 = en2[c];
    for (int wi = rslice; wi < cnt; wi += 16) {
        int row = wl[wi];
        const float4* xr = (const float4*)(x + (size_t)row * DIMS);
        float d = 0.f;
#pragma unroll
        for (int qq = 0; qq < 16; ++qq) {
            float4 ee = e[qq];
            float4 xx = xr[qq];
            d += ee.x * xx.x + ee.y * xx.y + ee.z * xx.z + ee.w * xx.w;
        }
        float bf_ = d + c0;
        int bc_ = c;
#pragma unroll
        for (int off = 1; off < 64; off <<= 1) {
            float of = __shfl_xor(bf_, off, 64);
            int   oc = __shfl_xor(bc_, off, 64);
            if (of > bf_ || (of == bf_ && oc < bc_)) { bf_ = of; bc_ = oc; }
        }
        if (lane == 0 && bf_ >= nbv[row] - GAP_THR) {
            unsigned int u = __float_as_uint(bf_);
            unsigned int sb = ((int)u < 0) ? ~u : (u | 0x80000000u);
            unsigned long long key = ((unsigned long long)sb << 32) | (unsigned int)(~bc_);
            atomicMax(&key8[row], key);
        }
    }
}

// ---------------------------------------------------------------------------
// Gather quantized rows, accumulate squared error, emit indices as floats.
// Last block (device-scope completion counter) also writes the final loss —
// fuses the former vq_loss launch.
// ---------------------------------------------------------------------------
__global__ void vq_gather(const float* __restrict__ x, const float* __restrict__ emb,
                          const int* __restrict__ idx_buf,
                          const unsigned long long* __restrict__ key8,
                          float* __restrict__ out, double* __restrict__ loss_acc,
                          int* __restrict__ done_count) {
    int row = blockIdx.x * blockDim.x + threadIdx.x;
    unsigned long long k = key8[row];
    int idx = k ? (int)(~(unsigned int)k) : idx_buf[row];
    const float4* ev = (const float4*)(emb + (size_t)idx * DIMS);
    const float4* xv = (const float4*)(x + (size_t)row * DIMS);
    float4* ov = (float4*)(out + (size_t)row * DIMS);
    float s = 0.f;
#pragma unroll
    for (int qq = 0; qq < 16; ++qq) {
        float4 ee = ev[qq];
        float4 xx = xv[qq];
        float dx = ee.x - xx.x, dy = ee.y - xx.y, dz = ee.z - xx.z, dw = ee.w - xx.w;
        s += dx * dx + dy * dy + dz * dz + dw * dw;
        ov[qq] = ee;
    }
#pragma unroll
    for (int off = 32; off > 0; off >>= 1) s += __shfl_down(s, off, 64);
    if ((threadIdx.x & 63) == 0) atomicAdd(loss_acc, (double)s);
    out[OUT_IDX + row] = (float)idx;
    __syncthreads();                        // all 4 wave-atomics of this block issued+drained
    if (threadIdx.x == 0) {
        __threadfence();                    // order our adds before the counter inc
        int d = atomicAdd(done_count, 1);
        if (d == (int)gridDim.x - 1) {
            double total = atomicAdd(loss_acc, 0.0);   // coherent read of final sum
            out[OUT_LOSS] = (float)(1.25 * total / (double)(N_ROWS * DIMS));
        }
    }
}

// ---------------------------------------------------------------------------
extern "C" void kernel_launch(void* const* d_in, const int* in_sizes, int n_in,
                              void* d_out, int out_size, void* d_ws, size_t ws_size,
                              hipStream_t stream) {
    const float* x   = (const float*)d_in[0];
    const float* emb = (const float*)d_in[1];
    float* out = (float*)d_out;
    char*  ws  = (char*)d_ws;

    short* efrag   = (short*)(ws + WS_EFRAG);
    float* en2     = (float*)(ws + WS_EN2);
    int*   idx_buf = (int*)(ws + WS_IDX);
    unsigned long long* key8 = (unsigned long long*)(ws + WS_KEY);
    float* bhb     = (float*)(ws + WS_BH);
    float* shb     = (float*)(ws + WS_SH);
    int*   chb     = (int*)(ws + WS_CH);
    double* loss_acc = (double*)(ws + WS_CTL);
    int*   wl_count  = (int*)(ws + WS_CTL + 8);
    int*   done_cnt  = (int*)(ws + WS_CTL + 12);
    int*   wl        = (int*)(ws + WS_WL);

    vq_prep<<<(NT * 64) / 256, 256, 0, stream>>>(emb, efrag, en2, (int4*)(ws + WS_CTL));  // 128 blocks
    vq_phase1<<<dim3(N_ROWS / 256, NQ), 256, 0, stream>>>(x, efrag, en2, bhb, shb, chb);  // 2048 blocks
    vq_merge<<<N_ROWS / 256, 256, 0, stream>>>(bhb, shb, chb, idx_buf, key8, bhb, wl, wl_count);
    vq_fixup<<<2048, 64, 0, stream>>>(x, emb, en2, bhb, key8, wl, wl_count);
    vq_gather<<<N_ROWS / 256, 256, 0, stream>>>(x, emb, idx_buf, key8, out, loss_acc, done_cnt);
}

// Round 5
// 191.278 us; speedup vs baseline: 1.0588x; 1.0355x over previous
//
#include <hip/hip_runtime.h>
#include <hip/hip_bf16.h>
#include <float.h>

// Problem constants
#define N_ROWS 32768          // 32 * 1024 query vectors
#define DIMS   64
#define K_EMB  8192
#define NT     (K_EMB / 16)   // 512 column tiles of 16
#define NQ     8              // K split into 8 slices -> grid 1024 = fully co-resident
#define NTQ    (NT / NQ)      // 64 tiles per slice (6 bits -> planted in mantissa)
#define TSTAGE 4              // tiles staged per barrier round (16 KB)
#define NSTAGE (NTQ / TSTAGE) // 16
#define RG     4              // row-groups (16 rows each) per wave -> 64 rows/wave
#define KEYMASK 0xFFFFFFC0u   // clear 6 low mantissa bits; plant within-slice tile idx
// err budget: split-bf16 mfma ~6.5e-4 + 2x key-mask (~5e-4 at |v|<=64) -> 3.5e-3
#define GAP_THR 3.5e-3f

typedef __attribute__((ext_vector_type(8))) short s8v;   // 8 bf16 (A/B frag)
typedef __attribute__((ext_vector_type(4))) float f4v;   // C/D frag
typedef __attribute__((ext_vector_type(4))) int   i4v;   // 16B load unit

// Workspace layout (bytes) — total ~5.8 MB
#define WS_EFRAG 0                              // 2 MiB
#define WS_EN2   (2 * 1024 * 1024)              // 8192 f32: -0.5*||e||^2
#define WS_IDX   (WS_EN2 + K_EMB * 4)           // 32768 i32 (merged idx)
#define WS_KEY   (WS_IDX + N_ROWS * 4)          // 32768 u64 fixup keys
#define WS_BH    (WS_KEY + N_ROWS * 8)          // [NQ][N] best key per slice (then nb)
#define WS_SH    (WS_BH + NQ * N_ROWS * 4)      // [NQ][N] second key
#define WS_CH    (WS_SH + NQ * N_ROWS * 4)      // [NQ][N] col idx
#define WS_CTL   (WS_CH + NQ * N_ROWS * 4)      // {double loss; int wl_count; int done}
#define WS_WL    (WS_CTL + 16)                  // worklist

// Output layout (float32 elements): [quantized | loss | indices]
#define OUT_LOSS (N_ROWS * DIMS)
#define OUT_IDX  (N_ROWS * DIMS + 1)

__device__ inline short bfh(float v) {
    __hip_bfloat16 h = __float2bfloat16(v);
    return __builtin_bit_cast(short, h);
}
__device__ inline float bff(short s) {
    __hip_bfloat16 h = __builtin_bit_cast(__hip_bfloat16, s);
    return __bfloat162float(h);
}

// ---------------------------------------------------------------------------
// Prep: embeddings -> MFMA B-frag layout (hi/lo bf16 split) + fused -||e||^2/2.
// B-frag: lane holds B[k=(lane>>4)*8+j][n=lane&15]. Frags: 0=hi k[0,32),
// 1=hi k[32,64), 2=lo k[0,32), 3=lo k[32,64). [tile][frag][lane][16B].
// Also zeroes the CTL block (loss acc + wl_count + done) — replaces a memset.
// ---------------------------------------------------------------------------
__global__ void vq_prep(const float* __restrict__ emb, short* __restrict__ efrag,
                        float* __restrict__ en2, int4* __restrict__ ctl) {
    if (blockIdx.x == 0 && threadIdx.x == 0) *ctl = make_int4(0, 0, 0, 0);
    int gid = blockIdx.x * 256 + threadIdx.x;   // NT*64 = 32768 threads
    int t = gid >> 6, lane = gid & 63;
    int m = lane & 15, q = lane >> 4;
    const float* er = emb + (size_t)(t * 16 + m) * DIMS;
    s8v hi0, lo0, hi1, lo1;
    float ss = 0.f;
#pragma unroll
    for (int j = 0; j < 8; ++j) {
        float v0 = er[q * 8 + j];
        float v1 = er[32 + q * 8 + j];
        ss += v0 * v0 + v1 * v1;
        short h0 = bfh(v0); lo0[j] = bfh(v0 - bff(h0)); hi0[j] = h0;
        short h1 = bfh(v1); lo1[j] = bfh(v1 - bff(h1)); hi1[j] = h1;
    }
    s8v* base = (s8v*)efrag + (size_t)t * 4 * 64;
    base[0 * 64 + lane] = hi0;
    base[1 * 64 + lane] = hi1;
    base[2 * 64 + lane] = lo0;
    base[3 * 64 + lane] = lo1;
    // reduce sum of squares across the 4 q-lanes sharing m
    ss += __shfl_xor(ss, 16, 64);
    ss += __shfl_xor(ss, 32, 64);
    if (q == 0) en2[t * 16 + m] = -0.5f * ss;
}

// ---------------------------------------------------------------------------
// Phase 1: LDS-staged split-bf16 MFMA distance + per-K-slice argmax/second.
// Grid (128, 8): blockIdx.x = row-block (256 rows), blockIdx.y = K-slice.
// 1024 blocks = 4 per CU x 256 CU: the whole grid is co-resident (32KB LDS x 4
// = 128KB <= 160KB), one round, no dispatch churn.
// Bookkeeping uses mantissa-planted keys: key = (bits(d) & KEYMASK) | tile.
// Per value: and_or + fmax + fmed3 (3 VALU, no index cndmask, no bc regs).
// Any ordering corrupted by the <=2^-17 perturbation has gap < GAP_THR and is
// repaired exactly in vq_fixup.
// Register economics: natural ~110 VGPR (R4 measured 124 incl. 16 bc regs).
// waves_per_eu(2,4): floor 2 never forces spill (R1/R3 lesson), target 4/EU.
// ---------------------------------------------------------------------------
__global__ __launch_bounds__(256)
__attribute__((amdgpu_waves_per_eu(2, 4))) void vq_phase1(
    const float* __restrict__ x, const short* __restrict__ efrag,
    const float* __restrict__ en2,
    float* __restrict__ bh, float* __restrict__ sh, int* __restrict__ ch) {
    __shared__ __align__(16) char lds[2][TSTAGE * 4096];   // 32 KB
    int tid = threadIdx.x, wid = tid >> 6, lane = tid & 63;
    int m = lane & 15, q = lane >> 4;
    int kh = blockIdx.y;
    int row0 = blockIdx.x * 256 + wid * 64;

    // A-frags for RG row-groups: A[m][k=quad*8+j], hi/lo, two K-halves of dims.
    s8v ahi[RG][2], alo[RG][2];
#pragma unroll
    for (int g = 0; g < RG; ++g) {
        const float* xr = x + (size_t)(row0 + g * 16 + m) * DIMS + q * 8;
#pragma unroll
        for (int j = 0; j < 8; ++j) {
            float v0 = xr[j], v1 = xr[32 + j];
            short h0 = bfh(v0); alo[g][0][j] = bfh(v0 - bff(h0)); ahi[g][0][j] = h0;
            short h1 = bfh(v1); alo[g][1][j] = bfh(v1 - bff(h1)); ahi[g][1][j] = h1;
        }
    }

    float best[RG][4], sec[RG][4];
#pragma unroll
    for (int g = 0; g < RG; ++g)
#pragma unroll
        for (int r = 0; r < 4; ++r) { best[g][r] = -FLT_MAX; sec[g][r] = -FLT_MAX; }

    const char* gsrc = (const char*)efrag + (size_t)kh * NTQ * 4096;

    // preload stage 0
#pragma unroll
    for (int i = 0; i < TSTAGE; ++i)
        __builtin_amdgcn_global_load_lds(
            (const __attribute__((address_space(1))) void*)(gsrc + i * 4096 + tid * 16),
            (__attribute__((address_space(3))) void*)(&lds[0][i * 4096 + tid * 16]),
            16, 0, 0);
    __syncthreads();

    for (int s = 0; s < NSTAGE; ++s) {
        int pb = s & 1;
        if (s + 1 < NSTAGE) {
            const char* gn = gsrc + (size_t)(s + 1) * TSTAGE * 4096;
#pragma unroll
            for (int i = 0; i < TSTAGE; ++i)
                __builtin_amdgcn_global_load_lds(
                    (const __attribute__((address_space(1))) void*)(gn + i * 4096 + tid * 16),
                    (__attribute__((address_space(3))) void*)(&lds[pb ^ 1][i * 4096 + tid * 16]),
                    16, 0, 0);
        }
        const i4v* B = (const i4v*)(lds[pb]);
        const float* ep = en2 + (size_t)(kh * NTQ + s * TSTAGE) * 16 + m;
#pragma unroll
        for (int tt = 0; tt < TSTAGE; ++tt) {
            i4v b0 = B[tt * 256 + 0 * 64 + lane];
            i4v b1 = B[tt * 256 + 1 * 64 + lane];
            i4v b2 = B[tt * 256 + 2 * 64 + lane];
            i4v b3 = B[tt * 256 + 3 * 64 + lane];
            float c0 = ep[tt * 16];
            unsigned code = (unsigned)(s * TSTAGE + tt);   // uniform, 0..63
            f4v cinit = {c0, c0, c0, c0};   // C init = -||e_col||^2 / 2
#pragma unroll
            for (int g = 0; g < RG; ++g) {
                f4v acc;
                acc = __builtin_amdgcn_mfma_f32_16x16x32_bf16(ahi[g][0], __builtin_bit_cast(s8v, b0), cinit, 0, 0, 0);
                acc = __builtin_amdgcn_mfma_f32_16x16x32_bf16(ahi[g][1], __builtin_bit_cast(s8v, b1), acc, 0, 0, 0);
                acc = __builtin_amdgcn_mfma_f32_16x16x32_bf16(ahi[g][0], __builtin_bit_cast(s8v, b2), acc, 0, 0, 0);
                acc = __builtin_amdgcn_mfma_f32_16x16x32_bf16(ahi[g][1], __builtin_bit_cast(s8v, b3), acc, 0, 0, 0);
                acc = __builtin_amdgcn_mfma_f32_16x16x32_bf16(alo[g][0], __builtin_bit_cast(s8v, b0), acc, 0, 0, 0);
                acc = __builtin_amdgcn_mfma_f32_16x16x32_bf16(alo[g][1], __builtin_bit_cast(s8v, b1), acc, 0, 0, 0);
#pragma unroll
                for (int r = 0; r < 4; ++r) {   // C/D: col=lane&15, row=quad*4+r
                    // key = distance with tile idx planted in 6 low mantissa bits
                    float kf = __uint_as_float(
                        (__float_as_uint(acc[r]) & KEYMASK) | code);  // v_and_or_b32
                    sec[g][r]  = __builtin_amdgcn_fmed3f(kf, sec[g][r], best[g][r]);
                    best[g][r] = fmaxf(best[g][r], kf);
                }
            }
        }
        __syncthreads();
    }

    // Reduce (best, second) keys across the 16 col-lanes of each quad.
    // Winner lane identified by bit-equality ballot; it reconstructs the col.
#pragma unroll
    for (int g = 0; g < RG; ++g)
#pragma unroll
    for (int r = 0; r < 4; ++r) {
        float b = best[g][r], sv = sec[g][r];
#pragma unroll
        for (int off = 1; off < 16; off <<= 1) {
            float ob = __shfl_xor(b, off, 64);
            float os = __shfl_xor(sv, off, 64);
            sv = fmaxf(fminf(b, ob), fmaxf(sv, os));
            b  = fmaxf(b, ob);
        }
        unsigned long long bal =
            __ballot(__float_as_uint(best[g][r]) == __float_as_uint(b));
        int win = __ffsll(bal >> (q * 16)) - 1;   // lowest matching m in our group
        if (m == win) {
            int tl  = (int)(__float_as_uint(b) & 63u);
            int col = ((kh * NTQ + tl) << 4) | m;
            int o = kh * N_ROWS + row0 + g * 16 + q * 4 + r;
            bh[o] = b; sh[o] = sv; ch[o] = col;
        }
    }
}

// ---------------------------------------------------------------------------
// Merge the NQ K-slices per row; store merged best key (for fixup prefilter);
// zero fixup keys; build worklist.
// ---------------------------------------------------------------------------
__global__ void vq_merge(const float* __restrict__ bh, const float* __restrict__ sh,
                         const int* __restrict__ ch, int* __restrict__ idx_buf,
                         unsigned long long* __restrict__ key8,
                         float* __restrict__ nbv,
                         int* __restrict__ wl, int* __restrict__ wl_count) {
    int row = blockIdx.x * 256 + threadIdx.x;
    float nb = bh[row];
    int   c  = ch[row];
    float ns = -FLT_MAX;
#pragma unroll
    for (int h = 1; h < NQ; ++h) {
        float b = bh[h * N_ROWS + row];
        int   cc = ch[h * N_ROWS + row];
        if (b > nb) { ns = nb; nb = b; c = cc; }
        else        { ns = fmaxf(ns, b); }
    }
#pragma unroll
    for (int h = 0; h < NQ; ++h) ns = fmaxf(ns, sh[h * N_ROWS + row]);
    idx_buf[row] = c;
    key8[row] = 0ULL;
    nbv[row] = nb;
    if (nb - ns < GAP_THR) {
        int pos = atomicAdd(wl_count, 1);
        wl[pos] = row;
    }
}

// ---------------------------------------------------------------------------
// Fixup: exact fp32 rescan. One wave per 64-column chunk; each lane owns one
// embedding column kept entirely in registers (16 float4), looping over the
// worklist rows (x row loads are wave-uniform). Candidates merged via
// atomicMax on packed (sortable(f) << 32 | ~idx) — exact argmax, ties->low
// idx. Prefilter: local max must be within GAP_THR of the merged approx best
// (exact winner always passes: |approx_key - exact| <= ~1.2e-3 < GAP_THR).
// Early-exit BEFORE the 16KB e-preload when this block's row-slice is empty.
// ---------------------------------------------------------------------------
__global__ __launch_bounds__(64) void vq_fixup(
    const float* __restrict__ x, const float* __restrict__ emb,
    const float* __restrict__ en2, const float* __restrict__ nbv,
    unsigned long long* __restrict__ key8,
    const int* __restrict__ wl, const int* __restrict__ wl_count) {
    int lane = threadIdx.x;                 // 64 threads = 1 wave
    int cchunk = blockIdx.x & 127;          // 128 col-chunks of 64
    int rslice = blockIdx.x >> 7;           // 16 row slices
    int cnt = *wl_count;
    if (rslice >= cnt) return;              // empty slice: skip e-preload
    int c = cchunk * 64 + lane;
    const float4* er = (const float4*)(emb + (size_t)c * DIMS);
    float4 e[16];
#pragma unroll
    for (int qq = 0; qq < 16; ++qq) e[qq] = er[qq];
    float c0 = en2[c];
    for (int wi = rslice; wi < cnt; wi += 16) {
        int row = wl[wi];
        const float4* xr = (const float4*)(x + (size_t)row * DIMS);
        float d = 0.f;
#pragma unroll
        for (int qq = 0; qq < 16; ++qq) {
            float4 ee = e[qq];
            float4 xx = xr[qq];
            d += ee.x * xx.x + ee.y * xx.y + ee.z * xx.z + ee.w * xx.w;
        }
        float bf_ = d + c0;
        int bc_ = c;
#pragma unroll
        for (int off = 1; off < 64; off <<= 1) {
            float of = __shfl_xor(bf_, off, 64);
            int   oc = __shfl_xor(bc_, off, 64);
            if (of > bf_ || (of == bf_ && oc < bc_)) { bf_ = of; bc_ = oc; }
        }
        if (lane == 0 && bf_ >= nbv[row] - GAP_THR) {
            unsigned int u = __float_as_uint(bf_);
            unsigned int sb = ((int)u < 0) ? ~u : (u | 0x80000000u);
            unsigned long long key = ((unsigned long long)sb << 32) | (unsigned int)(~bc_);
            atomicMax(&key8[row], key);
        }
    }
}

// ---------------------------------------------------------------------------
// Gather quantized rows, accumulate squared error, emit indices as floats.
// Last block (device-scope completion counter) also writes the final loss.
// ---------------------------------------------------------------------------
__global__ void vq_gather(const float* __restrict__ x, const float* __restrict__ emb,
                          const int* __restrict__ idx_buf,
                          const unsigned long long* __restrict__ key8,
                          float* __restrict__ out, double* __restrict__ loss_acc,
                          int* __restrict__ done_count) {
    int row = blockIdx.x * blockDim.x + threadIdx.x;
    unsigned long long k = key8[row];
    int idx = k ? (int)(~(unsigned int)k) : idx_buf[row];
    const float4* ev = (const float4*)(emb + (size_t)idx * DIMS);
    const float4* xv = (const float4*)(x + (size_t)row * DIMS);
    float4* ov = (float4*)(out + (size_t)row * DIMS);
    float s = 0.f;
#pragma unroll
    for (int qq = 0; qq < 16; ++qq) {
        float4 ee = ev[qq];
        float4 xx = xv[qq];
        float dx = ee.x - xx.x, dy = ee.y - xx.y, dz = ee.z - xx.z, dw = ee.w - xx.w;
        s += dx * dx + dy * dy + dz * dz + dw * dw;
        ov[qq] = ee;
    }
#pragma unroll
    for (int off = 32; off > 0; off >>= 1) s += __shfl_down(s, off, 64);
    if ((threadIdx.x & 63) == 0) atomicAdd(loss_acc, (double)s);
    out[OUT_IDX + row] = (float)idx;
    __syncthreads();                        // all 4 wave-atomics of this block issued
    if (threadIdx.x == 0) {
        __threadfence();                    // order our adds before the counter inc
        int d = atomicAdd(done_count, 1);
        if (d == (int)gridDim.x - 1) {
            double total = atomicAdd(loss_acc, 0.0);   // coherent read of final sum
            out[OUT_LOSS] = (float)(1.25 * total / (double)(N_ROWS * DIMS));
        }
    }
}

// ---------------------------------------------------------------------------
extern "C" void kernel_launch(void* const* d_in, const int* in_sizes, int n_in,
                              void* d_out, int out_size, void* d_ws, size_t ws_size,
                              hipStream_t stream) {
    const float* x   = (const float*)d_in[0];
    const float* emb = (const float*)d_in[1];
    float* out = (float*)d_out;
    char*  ws  = (char*)d_ws;

    short* efrag   = (short*)(ws + WS_EFRAG);
    float* en2     = (float*)(ws + WS_EN2);
    int*   idx_buf = (int*)(ws + WS_IDX);
    unsigned long long* key8 = (unsigned long long*)(ws + WS_KEY);
    float* bhb     = (float*)(ws + WS_BH);
    float* shb     = (float*)(ws + WS_SH);
    int*   chb     = (int*)(ws + WS_CH);
    double* loss_acc = (double*)(ws + WS_CTL);
    int*   wl_count  = (int*)(ws + WS_CTL + 8);
    int*   done_cnt  = (int*)(ws + WS_CTL + 12);
    int*   wl        = (int*)(ws + WS_WL);

    vq_prep<<<(NT * 64) / 256, 256, 0, stream>>>(emb, efrag, en2, (int4*)(ws + WS_CTL));  // 128 blocks
    vq_phase1<<<dim3(N_ROWS / 256, NQ), 256, 0, stream>>>(x, efrag, en2, bhb, shb, chb);  // 1024 blocks
    vq_merge<<<N_ROWS / 256, 256, 0, stream>>>(bhb, shb, chb, idx_buf, key8, bhb, wl, wl_count);
    vq_fixup<<<2048, 64, 0, stream>>>(x, emb, en2, bhb, key8, wl, wl_count);
    vq_gather<<<N_ROWS / 256, 256, 0, stream>>>(x, emb, idx_buf, key8, out, loss_acc, done_cnt);
}